// Round 2
// baseline (595.841 us; speedup 1.0000x reference)
//
#include <hip/hip_runtime.h>
#include <stddef.h>

#define TT 2048
#define NN 4096
#define LSEG 64
#define NSEG (TT / LSEG)   // 32
#define ABLK 16            // phase-A blocks (each redundantly simulates all N)
#define ATPB 1024          // phase-A threads/block
#define NPT 4              // neurons per thread (ATPB*NPT == NN)
#define TPB 256
#define NOFIRE 0xFFFFFFFEu

// ---------------- Phase A: exact coupled simulation, zero cross-block sync ----
// 16 blocks; EACH block simulates all 4096 neurons in registers (1024 thr x 4).
// The per-step global decision (fire?, argmin idx) is computed redundantly and
// identically in every block via an intra-block reduce (integer-exact), so no
// inter-block communication exists. Block b writes only ys slice
// [b*256, b*256+256). Arithmetic is op-for-op identical to the verified R1
// kernel (contract off, precise expf/logf) => bit-identical decisions.
__global__ __launch_bounds__(ATPB) void phaseA(
    const float* __restrict__ ts, const float* __restrict__ inp,
    const float* __restrict__ w, const float* __restrict__ v0,
    const float* __restrict__ i0, const float* __restrict__ mu,
    const float* __restrict__ s0u, const float* __restrict__ ru,
    const int* __restrict__ mx, float* __restrict__ ys,
    unsigned int* __restrict__ hdr)
{
#pragma clang fp contract(off)
  const int tid = threadIdx.x;
  const int bid = blockIdx.x;
  const float dt = ts[1] - ts[0];
  const float mu1 = mu[0], mu2 = mu[1];
  const int maxs = mx[0];

  // output slice mapping: neuron n = tid + k*1024; block writes [bid*256, +256)
  const int kw = bid >> 2;                    // k-slot that holds slice neurons
  const bool wr = ((tid >> 8) == (bid & 3));  // thread owns a slice neuron
  const int nw = bid * 256 + (tid & 255);     // its global neuron index

  float v[NPT], ci[NPT], s[NPT], wv[NPT], inpv[NPT], ruv[NPT];
  bool aw[NPT];
#pragma unroll
  for (int k = 0; k < NPT; ++k) {
    int n = tid + k * ATPB;
    v[k] = v0[n];
    ci[k] = i0[n];
    s[k] = logf(s0u[n] + 1e-12f) - 0.01f;
    wv[k] = 0.0f; aw[k] = false;
    inpv[k] = inp[n];   // row 0 prefetched
    ruv[k]  = ru[n];
  }
  int nsp = 0, t_stop = TT;

  __shared__ unsigned int sh_w[2][ATPB / 64];   // double-buffered: 1 barrier/step

  for (int t = 0; t < TT; ++t) {
    // prefetch next row (consumed next iteration)
    float inpn[NPT], run[NPT];
    if (t + 1 < TT) {
#pragma unroll
      for (int k = 0; k < NPT; ++k) {
        size_t o = (size_t)(t + 1) * NN + tid + k * ATPB;
        inpn[k] = inp[o]; run[k] = ru[o];
      }
    } else {
#pragma unroll
      for (int k = 0; k < NPT; ++k) { inpn[k] = 0.0f; run[k] = 0.0f; }
    }

    float sn[NPT]; bool ev[NPT];
    unsigned int m = NOFIRE;
#pragma unroll
    for (int k = 0; k < NPT; ++k) {
      float sig = 1.0f / (1.0f + expf(-v[k]));
      sn[k] = s[k] + dt * sig;
      ev[k] = sn[k] >= 0.0f;
      unsigned int cand = ev[k] ? (unsigned int)(tid + k * ATPB) : NOFIRE;
      m = m < cand ? m : cand;
    }

    bool coupled = (nsp < maxs);   // uniform across all threads/blocks
    unsigned int gm = NOFIRE;
    if (coupled) {
#pragma unroll
      for (int off = 32; off > 0; off >>= 1) {
        unsigned int o = (unsigned int)__shfl_down((int)m, off, 64);
        m = m < o ? m : o;
      }
      if ((tid & 63) == 0) sh_w[t & 1][tid >> 6] = m;
      __syncthreads();
      unsigned int bm = sh_w[t & 1][0];
#pragma unroll
      for (int j = 1; j < ATPB / 64; ++j) {
        unsigned int x = sh_w[t & 1][j];
        bm = bm < x ? bm : x;
      }
      gm = bm;
    }

    // resolve last step's pending w-row add (gather issued a full iter ago)
    float fi[NPT];
#pragma unroll
    for (int k = 0; k < NPT; ++k) fi[k] = aw[k] ? (ci[k] + wv[k]) : ci[k];

    // deferred store of ys[t-1] (now that i is final)
    if (t > 0 && wr) {
      size_t o = ((size_t)(t - 1) * NN + nw) * 3;
      ys[o] = v[kw]; ys[o + 1] = fi[kw]; ys[o + 2] = s[kw];
    }

    // step-t drift (numpy op order, no contraction)
    float vn[NPT], in_[NPT];
#pragma unroll
    for (int k = 0; k < NPT; ++k) {
      vn[k] = v[k] + dt * (mu1 * (fi[k] - v[k]) + mu1 * inpv[k]);
      in_[k] = fi[k] + dt * (-mu2 * fi[k]);
    }

    bool fire = coupled && (gm < (unsigned int)NN);
#pragma unroll
    for (int k = 0; k < NPT; ++k) aw[k] = false;
    if (fire) {
      ++nsp;
#pragma unroll
      for (int k = 0; k < NPT; ++k)
        wv[k] = w[(size_t)gm * NN + tid + k * ATPB];  // consumed NEXT iter
#pragma unroll
      for (int k = 0; k < NPT; ++k) {
        if (ev[k]) { v[k] = vn[k] - 1.0f; s[k] = logf(ruv[k] + 1e-12f) - 0.01f; }
        else       { v[k] = vn[k]; s[k] = sn[k]; aw[k] = true; }
      }
    } else {
#pragma unroll
      for (int k = 0; k < NPT; ++k) { v[k] = vn[k]; s[k] = sn[k]; }
    }
#pragma unroll
    for (int k = 0; k < NPT; ++k) { ci[k] = in_[k]; inpv[k] = inpn[k]; ruv[k] = run[k]; }

    if (nsp >= maxs && ((t + 1) & (LSEG - 1)) == 0) { t_stop = t + 1; break; }
  }

  // flush final deferred store
  if (wr) {
    float f = aw[kw] ? (ci[kw] + wv[kw]) : ci[kw];
    size_t o = ((size_t)(t_stop - 1) * NN + nw) * 3;
    ys[o] = v[kw]; ys[o + 1] = f; ys[o + 2] = s[kw];
  }
  if (bid == 0 && tid == 0) hdr[0] = (unsigned int)t_stop;
}

// ---------------- Phase B: decoupled closed-form tail ----------------
// P1: per (neuron, segment): C = affine const so v_{(g+1)L} = a^L v_{gL} + C.
__global__ __launch_bounds__(TPB) void p1_segc(
    const float* __restrict__ ts, const float* __restrict__ inp,
    const float* __restrict__ mu, const float* __restrict__ ys,
    const unsigned int* __restrict__ hdr, float* __restrict__ buf1)
{
  unsigned int Kp = hdr[0];
  unsigned int g0 = Kp / LSEG;
  unsigned int g = blockIdx.x >> 4;
  if (g < g0) return;
  int n = (blockIdx.x & 15) * TPB + threadIdx.x;
  float dt = ts[1] - ts[0];
  float mu1 = mu[0], mu2 = mu[1];
  float a = 1.0f - dt * mu1, b = dt * mu1, r = 1.0f - dt * mu2;
  float ibase = ys[((size_t)(Kp - 1) * NN + n) * 3 + 1];
  float ij = ibase * powf(r, (float)((int)(g * LSEG) - (int)Kp));
  float c = 0.0f;
  size_t base = (size_t)(g * LSEG) * NN + n;
  for (int j = 0; j < LSEG; ++j) {
    float x = inp[base + (size_t)j * NN];
    c = a * c + b * (ij + x);
    ij *= r;
  }
  buf1[(size_t)g * NN + n] = c;
}

// P2: per neuron, scan segment-boundary v (in place -> v at segment start)
__global__ __launch_bounds__(TPB) void p2_scanv(
    const float* __restrict__ ts, const float* __restrict__ mu,
    const float* __restrict__ ys, const unsigned int* __restrict__ hdr,
    float* __restrict__ buf1)
{
  unsigned int Kp = hdr[0];
  unsigned int g0 = Kp / LSEG;
  if (g0 >= NSEG) return;
  int n = blockIdx.x * TPB + threadIdx.x;
  float dt = ts[1] - ts[0];
  float mu1 = mu[0];
  float a = 1.0f - dt * mu1;
  float aL = a;
  for (int k = 0; k < 6; ++k) aL *= aL;   // a^64
  float v = ys[((size_t)(Kp - 1) * NN + n) * 3 + 0];
  for (unsigned int g = g0; g < NSEG; ++g) {
    float cg = buf1[(size_t)g * NN + n];
    buf1[(size_t)g * NN + n] = v;
    v = aL * v + cg;
  }
}

// P3a: per (neuron, segment): replay 64 steps, accumulate sigma-sum only.
__global__ __launch_bounds__(TPB) void p3a_sigma(
    const float* __restrict__ ts, const float* __restrict__ inp,
    const float* __restrict__ mu, const unsigned int* __restrict__ hdr,
    const float* __restrict__ buf1, const float* __restrict__ ys,
    float* __restrict__ buf2)
{
  unsigned int Kp = hdr[0];
  unsigned int g0 = Kp / LSEG;
  unsigned int g = blockIdx.x >> 4;
  if (g < g0) return;
  int n = (blockIdx.x & 15) * TPB + threadIdx.x;
  float dt = ts[1] - ts[0];
  float mu1 = mu[0], mu2 = mu[1];
  float r = 1.0f - dt * mu2;
  float v = buf1[(size_t)g * NN + n];
  float ibase = ys[((size_t)(Kp - 1) * NN + n) * 3 + 1];
  float i = ibase * powf(r, (float)((int)(g * LSEG) - (int)Kp));
  float sl = 0.0f;
  size_t base = (size_t)(g * LSEG) * NN + n;
  for (int j = 0; j < LSEG; ++j) {
    float x = inp[base + (size_t)j * NN];
    float sig = 1.0f / (1.0f + expf(-v));
    sl = sl + dt * sig;
    float vn = v + dt * (mu1 * (i - v) + mu1 * x);
    float in_ = i + dt * (-mu2 * i);
    v = vn; i = in_;
  }
  buf2[(size_t)g * NN + n] = sl;
}

// P4: per neuron, scan sigma-sums -> s at segment starts (in place)
__global__ __launch_bounds__(TPB) void p4_scans(
    const float* __restrict__ ys, const unsigned int* __restrict__ hdr,
    float* __restrict__ buf2)
{
  unsigned int Kp = hdr[0];
  unsigned int g0 = Kp / LSEG;
  if (g0 >= NSEG) return;
  int n = blockIdx.x * TPB + threadIdx.x;
  float s = ys[((size_t)(Kp - 1) * NN + n) * 3 + 2];
  for (unsigned int g = g0; g < NSEG; ++g) {
    float t = buf2[(size_t)g * NN + n];
    buf2[(size_t)g * NN + n] = s;
    s += t;
  }
}

// P3b: replay again with known (v,s) segment starts; write final v,i,s to ys.
__global__ __launch_bounds__(TPB) void p3b_write(
    const float* __restrict__ ts, const float* __restrict__ inp,
    const float* __restrict__ mu, const unsigned int* __restrict__ hdr,
    const float* __restrict__ buf1, const float* __restrict__ buf2,
    const float* __restrict__ ysr, float* __restrict__ ys)
{
  unsigned int Kp = hdr[0];
  unsigned int g0 = Kp / LSEG;
  unsigned int g = blockIdx.x >> 4;
  if (g < g0) return;
  int n = (blockIdx.x & 15) * TPB + threadIdx.x;
  float dt = ts[1] - ts[0];
  float mu1 = mu[0], mu2 = mu[1];
  float r = 1.0f - dt * mu2;
  float v = buf1[(size_t)g * NN + n];
  float s = buf2[(size_t)g * NN + n];
  float ibase = ysr[((size_t)(Kp - 1) * NN + n) * 3 + 1];
  float i = ibase * powf(r, (float)((int)(g * LSEG) - (int)Kp));
  for (int j = 0; j < LSEG; ++j) {
    size_t t = (size_t)g * LSEG + j;
    float x = inp[t * NN + n];
    float sig = 1.0f / (1.0f + expf(-v));
    s = s + dt * sig;
    float vn = v + dt * (mu1 * (i - v) + mu1 * x);
    float in_ = i + dt * (-mu2 * i);
    size_t o = (t * NN + n) * 3;
    ys[o] = vn; ys[o + 1] = in_; ys[o + 2] = s;
    v = vn; i = in_;
  }
}

extern "C" void kernel_launch(void* const* d_in, const int* in_sizes, int n_in,
                              void* d_out, int out_size, void* d_ws, size_t ws_size,
                              hipStream_t stream)
{
  (void)in_sizes; (void)n_in; (void)out_size; (void)ws_size;
  const float* ts  = (const float*)d_in[0];
  const float* inp = (const float*)d_in[1];
  const float* w   = (const float*)d_in[2];
  const float* v0  = (const float*)d_in[3];
  const float* i0  = (const float*)d_in[4];
  const float* mu  = (const float*)d_in[5];
  const float* s0u = (const float*)d_in[6];
  const float* ru  = (const float*)d_in[7];
  const int*   mx  = (const int*)d_in[8];
  float* ys = (float*)d_out;

  char* wsb = (char*)d_ws;
  unsigned int* hdr = (unsigned int*)wsb;                 // 64 B used
  float* buf1 = (float*)(wsb + 1024);                     // NSEG*NN*4 = 512 KB
  float* buf2 = buf1 + (size_t)NSEG * NN;                 // 512 KB

  phaseA<<<ABLK, ATPB, 0, stream>>>(ts, inp, w, v0, i0, mu, s0u, ru, mx, ys, hdr);
  p1_segc<<<NSEG * 16, TPB, 0, stream>>>(ts, inp, mu, ys, hdr, buf1);
  p2_scanv<<<NN / TPB, TPB, 0, stream>>>(ts, mu, ys, hdr, buf1);
  p3a_sigma<<<NSEG * 16, TPB, 0, stream>>>(ts, inp, mu, hdr, buf1, ys, buf2);
  p4_scans<<<NN / TPB, TPB, 0, stream>>>(ys, hdr, buf2);
  p3b_write<<<NSEG * 16, TPB, 0, stream>>>(ts, inp, mu, hdr, buf1, buf2, ys, ys);
}